// Round 6
// baseline (15133.252 us; speedup 1.0000x reference)
//
#include <hip/hip_runtime.h>
#include <hip/hip_fp16.h>
#include <cstdint>

// Problem constants
#define T_  256
#define B_  64
#define I_  1024
#define H_  1024
#define E_  4
#define C_  128
#define G4  4096   // 4*H

typedef _Float16 f16;
typedef _Float16 f16x8 __attribute__((ext_vector_type(8)));
typedef float    f32x4 __attribute__((ext_vector_type(4)));

__device__ __forceinline__ float sigmoidf_(float x) { return 1.f / (1.f + __expf(-x)); }

// ---------------- conversion f32 -> f16 (vectorized, grid-stride) -------------
__global__ void k_f32_to_f16(const float* __restrict__ src, f16* __restrict__ dst, int n8) {
    int i = blockIdx.x * blockDim.x + threadIdx.x;
    int stride = gridDim.x * blockDim.x;
    for (; i < n8; i += stride) {
        const float4* s = reinterpret_cast<const float4*>(src) + (size_t)i * 2;
        float4 a = s[0], b = s[1];
        f16x8 v = { (f16)a.x, (f16)a.y, (f16)a.z, (f16)a.w,
                    (f16)b.x, (f16)b.y, (f16)b.z, (f16)b.w };
        *reinterpret_cast<f16x8*>(dst + (size_t)i * 8) = v;
    }
}

// ---------------- mixed biases: gbias = coef@(bi+bh), bom = coef@bo ----------
__global__ void k_mix_biases(const float* __restrict__ coef, const float* __restrict__ bi,
                             const float* __restrict__ bh, const float* __restrict__ bo,
                             float* __restrict__ gbias, float* __restrict__ bom) {
    int idx = blockIdx.x * blockDim.x + threadIdx.x;
    int stride = gridDim.x * blockDim.x;
    for (int i = idx; i < B_ * G4; i += stride) {
        int b = i >> 12, o = i & (G4 - 1);
        float s = 0.f;
#pragma unroll
        for (int e = 0; e < 4; ++e) s += coef[b * 4 + e] * (bi[e * G4 + o] + bh[e * G4 + o]);
        gbias[i] = s;
    }
    for (int i = idx; i < B_ * C_; i += stride) {
        int b = i >> 7, c = i & (C_ - 1);
        float s = 0.f;
#pragma unroll
        for (int e = 0; e < 4; ++e) s += coef[b * 4 + e] * bo[e * C_ + c];
        bom[i] = s;
    }
}

// ---------------- h0 -> f16 --------------------------------------------------
__global__ void k_init_h0h(const float* __restrict__ h0, f16* __restrict__ h0h) {
    int i = blockIdx.x * blockDim.x + threadIdx.x;
    if (i < B_ * H_) h0h[i] = (f16)h0[i];
}

// ---------------- xi GEMM: per-sample mixed input projection -----------------
template<bool XF16, bool WF16>
__global__ __launch_bounds__(256, 1) void k_xi_gemm(
        const f16* __restrict__ xh, const float* __restrict__ xf,
        const f16* __restrict__ Wih, const float* __restrict__ Wif,
        const float* __restrict__ coef, const float* __restrict__ gbias,
        f16* __restrict__ xi) {
    __shared__ f16 As[256 * 72];
    __shared__ f16 Bs[128 * 72];
    const int nt = blockIdx.x;      // 0..31  (128-col tile of 4096)
    const int b  = blockIdx.y;      // 0..63
    const int tid = threadIdx.x;
    const int lane = tid & 63, wave = tid >> 6;
    const int wr = wave >> 1, wc = wave & 1;

    float cf[4];
#pragma unroll
    for (int e = 0; e < 4; ++e) cf[e] = coef[b * 4 + e];

    f32x4 acc[8][4];
#pragma unroll
    for (int mi = 0; mi < 8; ++mi)
#pragma unroll
        for (int ni = 0; ni < 4; ++ni) acc[mi][ni] = 0.f;

    for (int kk = 0; kk < I_; kk += 64) {
        __syncthreads();
#pragma unroll
        for (int it = 0; it < 8; ++it) {
            int chunk = it * 256 + tid;
            int row = chunk >> 3, c8 = chunk & 7;
            if constexpr (XF16) {
                *reinterpret_cast<f16x8*>(&As[row * 72 + c8 * 8]) =
                    *reinterpret_cast<const f16x8*>(&xh[((size_t)row * B_ + b) * I_ + kk + c8 * 8]);
            } else {
                const float4* p = reinterpret_cast<const float4*>(&xf[((size_t)row * B_ + b) * I_ + kk + c8 * 8]);
                float4 a = p[0], bq = p[1];
                f16x8 v = { (f16)a.x, (f16)a.y, (f16)a.z, (f16)a.w,
                            (f16)bq.x, (f16)bq.y, (f16)bq.z, (f16)bq.w };
                *reinterpret_cast<f16x8*>(&As[row * 72 + c8 * 8]) = v;
            }
        }
#pragma unroll
        for (int it = 0; it < 4; ++it) {
            int chunk = it * 256 + tid;
            int n = chunk >> 3, c8 = chunk & 7;
            if constexpr (WF16) {
                size_t base = ((size_t)(nt * 128 + n)) * I_ + kk + c8 * 8;
                f16 c0 = (f16)cf[0], c1 = (f16)cf[1], c2 = (f16)cf[2], c3 = (f16)cf[3];
                f16x8 w0 = *reinterpret_cast<const f16x8*>(&Wih[base]);
                f16x8 w1 = *reinterpret_cast<const f16x8*>(&Wih[base + (size_t)1 * G4 * I_]);
                f16x8 w2 = *reinterpret_cast<const f16x8*>(&Wih[base + (size_t)2 * G4 * I_]);
                f16x8 w3 = *reinterpret_cast<const f16x8*>(&Wih[base + (size_t)3 * G4 * I_]);
                f16x8 m = w0 * c0 + w1 * c1 + w2 * c2 + w3 * c3;
                *reinterpret_cast<f16x8*>(&Bs[n * 72 + c8 * 8]) = m;
            } else {
                size_t base = ((size_t)(nt * 128 + n)) * I_ + kk + c8 * 8;
                float m[8];
#pragma unroll
                for (int j = 0; j < 8; ++j) m[j] = 0.f;
#pragma unroll
                for (int e = 0; e < 4; ++e) {
                    const float4* p = reinterpret_cast<const float4*>(&Wif[base + (size_t)e * G4 * I_]);
                    float4 a = p[0], bq = p[1];
                    m[0] += cf[e] * a.x;  m[1] += cf[e] * a.y;
                    m[2] += cf[e] * a.z;  m[3] += cf[e] * a.w;
                    m[4] += cf[e] * bq.x; m[5] += cf[e] * bq.y;
                    m[6] += cf[e] * bq.z; m[7] += cf[e] * bq.w;
                }
                f16x8 v = { (f16)m[0], (f16)m[1], (f16)m[2], (f16)m[3],
                            (f16)m[4], (f16)m[5], (f16)m[6], (f16)m[7] };
                *reinterpret_cast<f16x8*>(&Bs[n * 72 + c8 * 8]) = v;
            }
        }
        __syncthreads();
#pragma unroll
        for (int ks = 0; ks < 2; ++ks) {
            int ko = ks * 32 + (lane >> 4) * 8;
            f16x8 a[8], bb[4];
#pragma unroll
            for (int mi = 0; mi < 8; ++mi)
                a[mi] = *reinterpret_cast<const f16x8*>(&As[(wr * 128 + mi * 16 + (lane & 15)) * 72 + ko]);
#pragma unroll
            for (int ni = 0; ni < 4; ++ni)
                bb[ni] = *reinterpret_cast<const f16x8*>(&Bs[(wc * 64 + ni * 16 + (lane & 15)) * 72 + ko]);
#pragma unroll
            for (int mi = 0; mi < 8; ++mi)
#pragma unroll
                for (int ni = 0; ni < 4; ++ni)
                    acc[mi][ni] = __builtin_amdgcn_mfma_f32_16x16x32_f16(a[mi], bb[ni], acc[mi][ni], 0, 0, 0);
        }
    }
#pragma unroll
    for (int mi = 0; mi < 8; ++mi)
#pragma unroll
        for (int ni = 0; ni < 4; ++ni)
#pragma unroll
            for (int j = 0; j < 4; ++j) {
                int t = wr * 128 + mi * 16 + (lane >> 4) * 4 + j;
                int o = nt * 128 + wc * 64 + ni * 16 + (lane & 15);
                float v = acc[mi][ni][j] + gbias[b * G4 + o];
                xi[((size_t)t * B_ + b) * G4 + o] = (f16)v;
            }
}

// ---------------- grid barrier (tree, fresh counters per step) ---------------
__device__ __forceinline__ void grid_barrier(int* __restrict__ bar, int t, int jb) {
    __threadfence();
    __syncthreads();
    if (threadIdx.x == 0) {
        int* leaf = bar + t * 9 + (jb & 7);
        int* root = bar + t * 9 + 8;
        int prev = __hip_atomic_fetch_add(leaf, 1, __ATOMIC_ACQ_REL, __HIP_MEMORY_SCOPE_AGENT);
        if (prev == 31)
            __hip_atomic_fetch_add(root, 1, __ATOMIC_ACQ_REL, __HIP_MEMORY_SCOPE_AGENT);
        while (__hip_atomic_load(root, __ATOMIC_RELAXED, __HIP_MEMORY_SCOPE_AGENT) != 8)
            __builtin_amdgcn_s_sleep(2);
        (void)__hip_atomic_load(root, __ATOMIC_ACQUIRE, __HIP_MEMORY_SCOPE_AGENT);
    }
    __syncthreads();
}

// ---------------- persistent recurrence (cooperative, 256 blocks x 512 thr) --
// Block jb owns h-cols jb*4..+4. 8 waves: wave w = (expert e=w&3, K-half
// kh=w>>2). Each wave holds its 16 B-fragments (K-chunk parity split:
// fragment K covers h-cols K*64 + kh*32 + hi8) in 16 NAMED f16x8 = 64 VGPR
// -> total live set ~115 < the 128-VGPR default pressure target, so the
// compiler has no reason to remat/spill (R5 failure mode). asm-volatile pin
// makes the loads non-rematerializable outright.
// Per step: double-buffered LDS A-tile (64x64 of h_prev, 1 f16x8/thread),
// 4 MFMA per wave per tile, LDS 8-way expert/K-half mix, cell update,
// h[t] -> xi[t] gate-0 overlay, tree grid-barrier.

#define AL(ABUF, MI) \
    (*reinterpret_cast<const f16x8*>(&ABUF[((MI) * 16 + l15) * 72 + ko]))

#define MMONE(ABUF, BW) \
    acc0 = __builtin_amdgcn_mfma_f32_16x16x32_f16(AL(ABUF, 0), BW, acc0, 0, 0, 0); \
    acc1 = __builtin_amdgcn_mfma_f32_16x16x32_f16(AL(ABUF, 1), BW, acc1, 0, 0, 0); \
    acc2 = __builtin_amdgcn_mfma_f32_16x16x32_f16(AL(ABUF, 2), BW, acc2, 0, 0, 0); \
    acc3 = __builtin_amdgcn_mfma_f32_16x16x32_f16(AL(ABUF, 3), BW, acc3, 0, 0, 0);

// K-step: prefetch tile KK+1 (one f16x8/thread), MFMA on tile KK, write, sync
#define KSTEP(KK, AB, AW, BW) { \
    const f16x8 pA = *reinterpret_cast<const f16x8*>(&hprev[(size_t)sr * hstr + ((KK) + 1) * 64 + s8]); \
    MMONE(AB, BW); \
    *reinterpret_cast<f16x8*>(&AW[sr * 72 + s8]) = pA; \
    __syncthreads(); \
}

__global__ __launch_bounds__(512, 1) void k_rec_persist(
        const f16* __restrict__ Whh, const f16* __restrict__ h0h,
        const float* __restrict__ c0, f16* xi, const float* __restrict__ coef,
        float* __restrict__ out, int* __restrict__ bar) {
    __shared__ f16 As0[64 * 72];
    __shared__ f16 As1[64 * 72];
    __shared__ float gl[8][64][17];
    const int jb = blockIdx.x;
    const int tid = threadIdx.x, lane = tid & 63, w = tid >> 6;   // 8 waves
    const int ex = w & 3, kh = w >> 2;                            // expert, K-half
    const int l15 = lane & 15, hi8 = (lane >> 4) * 8;
    const int ko = kh * 32 + hi8;                                 // LDS A k-offset

    // cell-update identity (threads 0..255 only)
    const int bb = tid >> 2, cl = tid & 3;
    const int col = jb * 4 + cl;
    float c_reg = 0.f;
    float4 cf4 = {0.f, 0.f, 0.f, 0.f};
    if (tid < 256) {
        c_reg = c0[bb * H_ + col];
        cf4 = *reinterpret_cast<const float4*>(&coef[bb * 4]);
    }

    // Wh B-fragments in 16 NAMED registers; fragment K covers h-cols
    // K*64 + kh*32 + hi8 .. +8, rows (gate,col) = l15 for expert ex
    const size_t grow = (size_t)ex * G4 + (size_t)(l15 >> 2) * H_ + jb * 4 + (l15 & 3);
    const f16* wp = Whh + grow * H_ + ko;
#define LOADW(K) f16x8 bw##K = *reinterpret_cast<const f16x8*>(wp + (size_t)(K) * 64); \
                 asm volatile("" : "+v"(bw##K));
    LOADW(0)  LOADW(1)  LOADW(2)  LOADW(3)  LOADW(4)  LOADW(5)  LOADW(6)  LOADW(7)
    LOADW(8)  LOADW(9)  LOADW(10) LOADW(11) LOADW(12) LOADW(13) LOADW(14) LOADW(15)
#undef LOADW

    // A-staging identity: 512 threads cover 64 rows x 64 cols, 1 f16x8 each
    const int sr = tid >> 3, s8 = (tid & 7) * 8;

    for (int t = 0; t < T_; ++t) {
        const f16* hprev = (t == 0) ? h0h : (xi + (size_t)(t - 1) * B_ * G4);
        const size_t hstr = (t == 0) ? (size_t)H_ : (size_t)G4;

        // early xi gate loads (epilogue operands; latency hides under K-loop)
        float xg0 = 0.f, xg1 = 0.f, xg2 = 0.f, xg3 = 0.f;
        if (tid < 256) {
            xg0 = (float)xi[((size_t)t * B_ + bb) * G4 + 0 * H_ + col];
            xg1 = (float)xi[((size_t)t * B_ + bb) * G4 + 1 * H_ + col];
            xg2 = (float)xi[((size_t)t * B_ + bb) * G4 + 2 * H_ + col];
            xg3 = (float)xi[((size_t)t * B_ + bb) * G4 + 3 * H_ + col];
        }

        // prologue: stage K-tile 0 into As0
        *reinterpret_cast<f16x8*>(&As0[sr * 72 + s8]) =
            *reinterpret_cast<const f16x8*>(&hprev[(size_t)sr * hstr + s8]);
        f32x4 acc0 = {0.f, 0.f, 0.f, 0.f}, acc1 = {0.f, 0.f, 0.f, 0.f};
        f32x4 acc2 = {0.f, 0.f, 0.f, 0.f}, acc3 = {0.f, 0.f, 0.f, 0.f};
        __syncthreads();

        KSTEP(0,  As0, As1, bw0)
        KSTEP(1,  As1, As0, bw1)
        KSTEP(2,  As0, As1, bw2)
        KSTEP(3,  As1, As0, bw3)
        KSTEP(4,  As0, As1, bw4)
        KSTEP(5,  As1, As0, bw5)
        KSTEP(6,  As0, As1, bw6)
        KSTEP(7,  As1, As0, bw7)
        KSTEP(8,  As0, As1, bw8)
        KSTEP(9,  As1, As0, bw9)
        KSTEP(10, As0, As1, bw10)
        KSTEP(11, As1, As0, bw11)
        KSTEP(12, As0, As1, bw12)
        KSTEP(13, As1, As0, bw13)
        KSTEP(14, As0, As1, bw14)
        MMONE(As1, bw15)   // last tile, no prefetch

        // park per-(expert,K-half) partials
#pragma unroll
        for (int j = 0; j < 4; ++j) {
            gl[w][0 * 16 + (lane >> 4) * 4 + j][l15] = acc0[j];
            gl[w][1 * 16 + (lane >> 4) * 4 + j][l15] = acc1[j];
            gl[w][2 * 16 + (lane >> 4) * 4 + j][l15] = acc2[j];
            gl[w][3 * 16 + (lane >> 4) * 4 + j][l15] = acc3[j];
        }
        __syncthreads();

        // mix experts (+ both K-halves) + cell update (threads 0..255)
        if (tid < 256) {
            float gate[4];
#pragma unroll
            for (int g = 0; g < 4; ++g) {
                int nn = g * 4 + cl;
                gate[g] = cf4.x * (gl[0][bb][nn] + gl[4][bb][nn]) +
                          cf4.y * (gl[1][bb][nn] + gl[5][bb][nn]) +
                          cf4.z * (gl[2][bb][nn] + gl[6][bb][nn]) +
                          cf4.w * (gl[3][bb][nn] + gl[7][bb][nn]);
            }
            gate[0] += xg0; gate[1] += xg1; gate[2] += xg2; gate[3] += xg3;
            float cn = sigmoidf_(gate[1]) * c_reg + sigmoidf_(gate[0]) * tanhf(gate[2]);
            float hn = sigmoidf_(gate[3]) * tanhf(cn);
            c_reg = cn;
            xi[((size_t)t * B_ + bb) * G4 + col] = (f16)hn;   // h[t] overlay
            if (t == T_ - 1) {
                out[(size_t)T_ * B_ * C_ + bb * H_ + col] = hn;
                out[(size_t)T_ * B_ * C_ + B_ * H_ + bb * H_ + col] = cn;
            }
        }
        if (t != T_ - 1) grid_barrier(bar, t, jb);
    }
}

// ---------------- output projection ------------------------------------------
__global__ __launch_bounds__(256, 1) void k_out_gemm(
        const f16* __restrict__ hs, const f16* __restrict__ Woh,
        const float* __restrict__ coef, const float* __restrict__ bom,
        float* __restrict__ out) {
    __shared__ f16 As[64 * 72];
    __shared__ f16 Bs[256 * 72];
    __shared__ float cfs[64][4];
    const int nt = blockIdx.x;   // 0..1
    const int t  = blockIdx.y;   // 0..255
    const int tid = threadIdx.x, lane = tid & 63, w = tid >> 6;
    cfs[tid >> 2][tid & 3] = coef[tid];

    f32x4 acc[4][4];
#pragma unroll
    for (int e = 0; e < 4; ++e)
#pragma unroll
        for (int mi = 0; mi < 4; ++mi) acc[e][mi] = 0.f;

    for (int kk = 0; kk < H_; kk += 64) {
        __syncthreads();
#pragma unroll
        for (int it = 0; it < 2; ++it) {   // A: hs[t] 64x64 (stride G4 overlay)
            int chunk = it * 256 + tid;
            int row = chunk >> 3, c8 = chunk & 7;
            *reinterpret_cast<f16x8*>(&As[row * 72 + c8 * 8]) =
                *reinterpret_cast<const f16x8*>(&hs[((size_t)t * B_ + row) * G4 + kk + c8 * 8]);
        }
#pragma unroll
        for (int it = 0; it < 8; ++it) {   // B: Wo rows e*C + nt*64 + n
            int chunk = it * 256 + tid;
            int r = chunk >> 3, c8 = chunk & 7;
            int e = r >> 6, nn = r & 63;
            size_t grow = (size_t)e * C_ + nt * 64 + nn;
            *reinterpret_cast<f16x8*>(&Bs[r * 72 + c8 * 8]) =
                *reinterpret_cast<const f16x8*>(&Woh[grow * H_ + kk + c8 * 8]);
        }
        __syncthreads();
#pragma unroll
        for (int ks = 0; ks < 2; ++ks) {
            int ko = ks * 32 + (lane >> 4) * 8;
            f16x8 a[4];
#pragma unroll
            for (int mi = 0; mi < 4; ++mi)
                a[mi] = *reinterpret_cast<const f16x8*>(&As[(mi * 16 + (lane & 15)) * 72 + ko]);
#pragma unroll
            for (int e = 0; e < 4; ++e) {
                f16x8 bf = *reinterpret_cast<const f16x8*>(&Bs[(e * 64 + w * 16 + (lane & 15)) * 72 + ko]);
#pragma unroll
                for (int mi = 0; mi < 4; ++mi)
                    acc[e][mi] = __builtin_amdgcn_mfma_f32_16x16x32_f16(a[mi], bf, acc[e][mi], 0, 0, 0);
            }
        }
    }
#pragma unroll
    for (int mi = 0; mi < 4; ++mi)
#pragma unroll
        for (int j = 0; j < 4; ++j) {
            int bb = mi * 16 + (lane >> 4) * 4 + j;
            int cc = nt * 64 + w * 16 + (lane & 15);
            float v = cfs[bb][0] * acc[0][mi][j] + cfs[bb][1] * acc[1][mi][j] +
                      cfs[bb][2] * acc[2][mi][j] + cfs[bb][3] * acc[3][mi][j];
            v += bom[bb * C_ + cc];
            out[((size_t)t * B_ + bb) * C_ + cc] = v;
        }
}

extern "C" void kernel_launch(void* const* d_in, const int* in_sizes, int n_in,
                              void* d_out, int out_size, void* d_ws, size_t ws_size,
                              hipStream_t stream) {
    const float* x    = (const float*)d_in[0];
    const float* h0   = (const float*)d_in[1];
    const float* c0   = (const float*)d_in[2];
    const float* coef = (const float*)d_in[3];
    const float* Wi   = (const float*)d_in[4];
    const float* bi   = (const float*)d_in[5];
    const float* Wh   = (const float*)d_in[6];
    const float* bh   = (const float*)d_in[7];
    const float* Wo   = (const float*)d_in[8];
    const float* bo   = (const float*)d_in[9];
    float* out = (float*)d_out;

    char* base = (char*)d_ws;
    size_t off = 0;
    auto carve = [&](size_t bytes) -> char* {
        char* r = base + off;
        off = (off + bytes + 255) & ~(size_t)255;
        return r;
    };
    const size_t SZ_XI  = (size_t)T_ * B_ * G4 * 2;   // 134.2 MB (gate-0 doubles as hs)
    const size_t SZ_WHH = (size_t)E_ * G4 * H_ * 2;   // 33.5 MB
    const size_t SZ_WOH = (size_t)E_ * C_ * H_ * 2;   // 1 MB
    const size_t SZ_BAR = (size_t)T_ * 9 * 4;         // barrier counters
    const size_t SZ_WIH = (size_t)E_ * G4 * I_ * 2;   // 33.5 MB (optional)
    const size_t SZ_XH  = (size_t)T_ * B_ * I_ * 2;   // 33.5 MB (optional)

    f16*   xi     = (f16*)carve(SZ_XI);
    f16*   Whh    = (f16*)carve(SZ_WHH);
    f16*   Woh    = (f16*)carve(SZ_WOH);
    f16*   h0h    = (f16*)carve((size_t)B_ * H_ * 2);
    float* gbias  = (float*)carve((size_t)B_ * G4 * 4);
    float* bom    = (float*)carve((size_t)B_ * C_ * 4);
    int*   bar    = (int*)carve(SZ_BAR);

    f16* Wih = nullptr;
    f16* xh  = nullptr;
    if (off + SZ_WIH + 256 <= ws_size) Wih = (f16*)carve(SZ_WIH);
    if (Wih && off + SZ_XH + 256 <= ws_size) xh = (f16*)carve(SZ_XH);
    (void)in_sizes; (void)n_in; (void)out_size;

    hipMemsetAsync(bar, 0, SZ_BAR, stream);

    if (xh)  k_f32_to_f16<<<2048, 256, 0, stream>>>(x,  xh,  (T_ * B_ * I_) / 8);
    if (Wih) k_f32_to_f16<<<2048, 256, 0, stream>>>(Wi, Wih, (E_ * G4 * I_) / 8);
    k_f32_to_f16<<<2048, 256, 0, stream>>>(Wh, Whh, (E_ * G4 * H_) / 8);
    k_f32_to_f16<<<512,  256, 0, stream>>>(Wo, Woh, (E_ * C_ * H_) / 8);
    k_mix_biases<<<512, 256, 0, stream>>>(coef, bi, bh, bo, gbias, bom);
    k_init_h0h<<<(B_ * H_ + 255) / 256, 256, 0, stream>>>(h0, h0h);

    dim3 gx(32, 64);
    if (xh)
        k_xi_gemm<true,  true ><<<gx, 256, 0, stream>>>(xh, nullptr, Wih, nullptr, coef, gbias, xi);
    else if (Wih)
        k_xi_gemm<false, true ><<<gx, 256, 0, stream>>>(nullptr, x, Wih, nullptr, coef, gbias, xi);
    else
        k_xi_gemm<false, false><<<gx, 256, 0, stream>>>(nullptr, x, nullptr, Wi, coef, gbias, xi);

    // persistent recurrence: one cooperative launch, 256 blocks x 512 threads
    {
        void* args[] = { (void*)&Whh, (void*)&h0h, (void*)&c0, (void*)&xi,
                         (void*)&coef, (void*)&out, (void*)&bar };
        hipLaunchCooperativeKernel((const void*)k_rec_persist, dim3(256), dim3(512),
                                   args, 0, stream);
    }

    dim3 go(2, 256);
    k_out_gemm<<<go, 256, 0, stream>>>(xi, Woh, coef, bom, out);
}

// Round 8
// 14901.289 us; speedup vs baseline: 1.0156x; 1.0156x over previous
//
#include <hip/hip_runtime.h>
#include <hip/hip_fp16.h>
#include <cstdint>

// Problem constants
#define T_  256
#define B_  64
#define I_  1024
#define H_  1024
#define E_  4
#define C_  128
#define G4  4096   // 4*H

typedef _Float16 f16;
typedef _Float16 f16x8 __attribute__((ext_vector_type(8)));
typedef float    f32x4 __attribute__((ext_vector_type(4)));

__device__ __forceinline__ float sigmoidf_(float x) { return 1.f / (1.f + __expf(-x)); }

// ---------------- conversion f32 -> f16 (vectorized, grid-stride) -------------
__global__ void k_f32_to_f16(const float* __restrict__ src, f16* __restrict__ dst, int n8) {
    int i = blockIdx.x * blockDim.x + threadIdx.x;
    int stride = gridDim.x * blockDim.x;
    for (; i < n8; i += stride) {
        const float4* s = reinterpret_cast<const float4*>(src) + (size_t)i * 2;
        float4 a = s[0], b = s[1];
        f16x8 v = { (f16)a.x, (f16)a.y, (f16)a.z, (f16)a.w,
                    (f16)b.x, (f16)b.y, (f16)b.z, (f16)b.w };
        *reinterpret_cast<f16x8*>(dst + (size_t)i * 8) = v;
    }
}

// ---------------- mixed biases: gbias = coef@(bi+bh), bom = coef@bo ----------
__global__ void k_mix_biases(const float* __restrict__ coef, const float* __restrict__ bi,
                             const float* __restrict__ bh, const float* __restrict__ bo,
                             float* __restrict__ gbias, float* __restrict__ bom) {
    int idx = blockIdx.x * blockDim.x + threadIdx.x;
    int stride = gridDim.x * blockDim.x;
    for (int i = idx; i < B_ * G4; i += stride) {
        int b = i >> 12, o = i & (G4 - 1);
        float s = 0.f;
#pragma unroll
        for (int e = 0; e < 4; ++e) s += coef[b * 4 + e] * (bi[e * G4 + o] + bh[e * G4 + o]);
        gbias[i] = s;
    }
    for (int i = idx; i < B_ * C_; i += stride) {
        int b = i >> 7, c = i & (C_ - 1);
        float s = 0.f;
#pragma unroll
        for (int e = 0; e < 4; ++e) s += coef[b * 4 + e] * bo[e * C_ + c];
        bom[i] = s;
    }
}

// ---------------- h0 -> f16 --------------------------------------------------
__global__ void k_init_h0h(const float* __restrict__ h0, f16* __restrict__ h0h) {
    int i = blockIdx.x * blockDim.x + threadIdx.x;
    if (i < B_ * H_) h0h[i] = (f16)h0[i];
}

// ---------------- xi GEMM: per-sample mixed input projection -----------------
template<bool XF16, bool WF16>
__global__ __launch_bounds__(256, 1) void k_xi_gemm(
        const f16* __restrict__ xh, const float* __restrict__ xf,
        const f16* __restrict__ Wih, const float* __restrict__ Wif,
        const float* __restrict__ coef, const float* __restrict__ gbias,
        f16* __restrict__ xi) {
    __shared__ f16 As[256 * 72];
    __shared__ f16 Bs[128 * 72];
    const int nt = blockIdx.x;      // 0..31  (128-col tile of 4096)
    const int b  = blockIdx.y;      // 0..63
    const int tid = threadIdx.x;
    const int lane = tid & 63, wave = tid >> 6;
    const int wr = wave >> 1, wc = wave & 1;

    float cf[4];
#pragma unroll
    for (int e = 0; e < 4; ++e) cf[e] = coef[b * 4 + e];

    f32x4 acc[8][4];
#pragma unroll
    for (int mi = 0; mi < 8; ++mi)
#pragma unroll
        for (int ni = 0; ni < 4; ++ni) acc[mi][ni] = 0.f;

    for (int kk = 0; kk < I_; kk += 64) {
        __syncthreads();
#pragma unroll
        for (int it = 0; it < 8; ++it) {
            int chunk = it * 256 + tid;
            int row = chunk >> 3, c8 = chunk & 7;
            if constexpr (XF16) {
                *reinterpret_cast<f16x8*>(&As[row * 72 + c8 * 8]) =
                    *reinterpret_cast<const f16x8*>(&xh[((size_t)row * B_ + b) * I_ + kk + c8 * 8]);
            } else {
                const float4* p = reinterpret_cast<const float4*>(&xf[((size_t)row * B_ + b) * I_ + kk + c8 * 8]);
                float4 a = p[0], bq = p[1];
                f16x8 v = { (f16)a.x, (f16)a.y, (f16)a.z, (f16)a.w,
                            (f16)bq.x, (f16)bq.y, (f16)bq.z, (f16)bq.w };
                *reinterpret_cast<f16x8*>(&As[row * 72 + c8 * 8]) = v;
            }
        }
#pragma unroll
        for (int it = 0; it < 4; ++it) {
            int chunk = it * 256 + tid;
            int n = chunk >> 3, c8 = chunk & 7;
            if constexpr (WF16) {
                size_t base = ((size_t)(nt * 128 + n)) * I_ + kk + c8 * 8;
                f16 c0 = (f16)cf[0], c1 = (f16)cf[1], c2 = (f16)cf[2], c3 = (f16)cf[3];
                f16x8 w0 = *reinterpret_cast<const f16x8*>(&Wih[base]);
                f16x8 w1 = *reinterpret_cast<const f16x8*>(&Wih[base + (size_t)1 * G4 * I_]);
                f16x8 w2 = *reinterpret_cast<const f16x8*>(&Wih[base + (size_t)2 * G4 * I_]);
                f16x8 w3 = *reinterpret_cast<const f16x8*>(&Wih[base + (size_t)3 * G4 * I_]);
                f16x8 m = w0 * c0 + w1 * c1 + w2 * c2 + w3 * c3;
                *reinterpret_cast<f16x8*>(&Bs[n * 72 + c8 * 8]) = m;
            } else {
                size_t base = ((size_t)(nt * 128 + n)) * I_ + kk + c8 * 8;
                float m[8];
#pragma unroll
                for (int j = 0; j < 8; ++j) m[j] = 0.f;
#pragma unroll
                for (int e = 0; e < 4; ++e) {
                    const float4* p = reinterpret_cast<const float4*>(&Wif[base + (size_t)e * G4 * I_]);
                    float4 a = p[0], bq = p[1];
                    m[0] += cf[e] * a.x;  m[1] += cf[e] * a.y;
                    m[2] += cf[e] * a.z;  m[3] += cf[e] * a.w;
                    m[4] += cf[e] * bq.x; m[5] += cf[e] * bq.y;
                    m[6] += cf[e] * bq.z; m[7] += cf[e] * bq.w;
                }
                f16x8 v = { (f16)m[0], (f16)m[1], (f16)m[2], (f16)m[3],
                            (f16)m[4], (f16)m[5], (f16)m[6], (f16)m[7] };
                *reinterpret_cast<f16x8*>(&Bs[n * 72 + c8 * 8]) = v;
            }
        }
        __syncthreads();
#pragma unroll
        for (int ks = 0; ks < 2; ++ks) {
            int ko = ks * 32 + (lane >> 4) * 8;
            f16x8 a[8], bb[4];
#pragma unroll
            for (int mi = 0; mi < 8; ++mi)
                a[mi] = *reinterpret_cast<const f16x8*>(&As[(wr * 128 + mi * 16 + (lane & 15)) * 72 + ko]);
#pragma unroll
            for (int ni = 0; ni < 4; ++ni)
                bb[ni] = *reinterpret_cast<const f16x8*>(&Bs[(wc * 64 + ni * 16 + (lane & 15)) * 72 + ko]);
#pragma unroll
            for (int mi = 0; mi < 8; ++mi)
#pragma unroll
                for (int ni = 0; ni < 4; ++ni)
                    acc[mi][ni] = __builtin_amdgcn_mfma_f32_16x16x32_f16(a[mi], bb[ni], acc[mi][ni], 0, 0, 0);
        }
    }
#pragma unroll
    for (int mi = 0; mi < 8; ++mi)
#pragma unroll
        for (int ni = 0; ni < 4; ++ni)
#pragma unroll
            for (int j = 0; j < 4; ++j) {
                int t = wr * 128 + mi * 16 + (lane >> 4) * 4 + j;
                int o = nt * 128 + wc * 64 + ni * 16 + (lane & 15);
                float v = acc[mi][ni][j] + gbias[b * G4 + o];
                xi[((size_t)t * B_ + b) * G4 + o] = (f16)v;
            }
}

// ---------------- grid barrier (tree, fresh counters per step) ---------------
__device__ __forceinline__ void grid_barrier(int* __restrict__ bar, int t, int jb) {
    __threadfence();
    __syncthreads();
    if (threadIdx.x == 0) {
        int* leaf = bar + t * 9 + (jb & 7);
        int* root = bar + t * 9 + 8;
        int prev = __hip_atomic_fetch_add(leaf, 1, __ATOMIC_ACQ_REL, __HIP_MEMORY_SCOPE_AGENT);
        if (prev == 31)
            __hip_atomic_fetch_add(root, 1, __ATOMIC_ACQ_REL, __HIP_MEMORY_SCOPE_AGENT);
        while (__hip_atomic_load(root, __ATOMIC_RELAXED, __HIP_MEMORY_SCOPE_AGENT) != 8)
            __builtin_amdgcn_s_sleep(2);
        (void)__hip_atomic_load(root, __ATOMIC_ACQUIRE, __HIP_MEMORY_SCOPE_AGENT);
    }
    __syncthreads();
}

// ---------------- persistent recurrence (cooperative, 256 x 512) -------------
// Block jb owns h-cols jb*4..+4. Its 131KB Whh slice lives in LDS (loaded once,
// f32->f16, XOR-swizzled). 8 waves = (expert w&3, M-half w>>2). Per step:
// double-buffered XOR-swizzled 64x64 A-tile of h_prev, per K-tile
// {2 B-frag + 4 A-frag ds_read_b128, 4 MFMA}, LDS expert mix (gl overlaid on
// A-buffers), cell update, h[t] -> xi[t] gate-0 overlay, tree grid-barrier.
//
// SWIZZLE (rule #21: same involution both sides): store puts within-row byte
// L at L ^ ((row&7)<<4); read must XOR the FULL within-row offset:
//   addr = rowbase + KC*128 + ((KS*64 + hi8*2) ^ swz)
// (KS*64 + hi8*2 occupies exactly bits 4..6 -> no carry; KC*128 is bits >=7.)
// R7 bug: ((hi8*2)^swz) + KS*64 carried into bit 7 when swz bit6 & KS=1.
//
// LDS pool: [W 131072][As0 8192][As1 8192 | gl 17408 overlays As0+As1+1KB]
#define POOL_SZ  148480
#define AS0_OFF  131072
#define AS1_OFF  (131072 + 8192)
#define GL_OFF   131072

#define BF(KC, KS) (*reinterpret_cast<const f16x8*>(pool + wrow + (KC) * 128 + (((KS) * 64 + koff) ^ swz)))
#define AF(AOFF, AROW, KS) (*reinterpret_cast<const f16x8*>(pool + (AOFF) + (AROW) + (((KS) * 64 + koff) ^ swz)))

#define KSTEP(KC, ROFF, WOFF) { \
    f16x8 pfA; \
    if ((KC) < 15) pfA = *reinterpret_cast<const f16x8*>(&hprev[(size_t)sr * hstr + ((KC) + 1) * 64 + soct * 8]); \
    const f16x8 b0 = BF(KC, 0), b1 = BF(KC, 1); \
    acc0 = __builtin_amdgcn_mfma_f32_16x16x32_f16(AF(ROFF, arow0, 0), b0, acc0, 0, 0, 0); \
    acc1 = __builtin_amdgcn_mfma_f32_16x16x32_f16(AF(ROFF, arow1, 0), b0, acc1, 0, 0, 0); \
    acc0 = __builtin_amdgcn_mfma_f32_16x16x32_f16(AF(ROFF, arow0, 1), b1, acc0, 0, 0, 0); \
    acc1 = __builtin_amdgcn_mfma_f32_16x16x32_f16(AF(ROFF, arow1, 1), b1, acc1, 0, 0, 0); \
    if ((KC) < 15) *reinterpret_cast<f16x8*>(pool + (WOFF) + sdst) = pfA; \
    __syncthreads(); \
}

__global__ __launch_bounds__(512, 1) void k_rec_persist(
        const float* __restrict__ Wh, const f16* __restrict__ h0h,
        const float* __restrict__ c0, f16* xi, const float* __restrict__ coef,
        float* __restrict__ out, int* __restrict__ bar) {
    __shared__ __attribute__((aligned(16))) char pool[POOL_SZ];
    float* gl = reinterpret_cast<float*>(pool + GL_OFF);   // [4][64][17]

    const int jb = blockIdx.x;
    const int tid = threadIdx.x, lane = tid & 63, w = tid >> 6;
    const int ex = w & 3, mh = w >> 2;                    // expert, M-half
    const int l15 = lane & 15, hi8 = (lane >> 4) * 8;

    // ---- one-time: Wh slice f32 -> f16 into swizzled LDS ----
    for (int i = tid; i < 8192; i += 512) {
        int r = i >> 7, oct = i & 127;                    // r = e*16+g*4+c, 128 octets of 8 f16
        int e = r >> 4, g = (r >> 2) & 3, c = r & 3;
        const float* src = &Wh[((size_t)e * G4 + g * H_ + jb * 4 + c) * H_ + oct * 8];
        float4 f0 = *reinterpret_cast<const float4*>(src);
        float4 f1 = *reinterpret_cast<const float4*>(src + 4);
        f16x8 v = { (f16)f0.x, (f16)f0.y, (f16)f0.z, (f16)f0.w,
                    (f16)f1.x, (f16)f1.y, (f16)f1.z, (f16)f1.w };
        int db = r * 2048 + ((oct * 16) ^ ((r & 7) << 4));
        *reinterpret_cast<f16x8*>(pool + db) = v;
    }

    // cell-update identity (threads 0..255)
    const int bb = tid >> 2, cl = tid & 3;
    const int col = jb * 4 + cl;
    float c_reg = 0.f;
    float4 cf4 = {0.f, 0.f, 0.f, 0.f};
    if (tid < 256) {
        c_reg = c0[bb * H_ + col];
        cf4 = *reinterpret_cast<const float4*>(&coef[bb * 4]);
    }

    // per-thread LDS bases; swizzle applied to FULL within-row offset at use
    const int swz   = (l15 & 7) << 4;
    const int koff  = hi8 * 2;                            // byte offset of k-octet, bits 4..5
    const int wrow  = (ex * 16 + l15) * 2048;             // W row base (row = B-frag n)
    const int arow0 = (mh * 32 + l15) * 128;              // A row base (row = b)
    const int arow1 = arow0 + 16 * 128;
    // staging identity: 512 threads x 16B cover 64 rows x 64 cols
    const int sr = tid >> 3, soct = tid & 7;
    const int sdst = sr * 128 + ((soct * 16) ^ ((sr & 7) << 4));

    __syncthreads();

    for (int t = 0; t < T_; ++t) {
        const f16* hprev = (t == 0) ? h0h : (xi + (size_t)(t - 1) * B_ * G4);
        const size_t hstr = (t == 0) ? (size_t)H_ : (size_t)G4;

        // early xi gate loads (epilogue operands; latency hides under K-loop)
        float xg0 = 0.f, xg1 = 0.f, xg2 = 0.f, xg3 = 0.f;
        if (tid < 256) {
            const f16* xp = &xi[((size_t)t * B_ + bb) * G4 + col];
            xg0 = (float)xp[0];      xg1 = (float)xp[H_];
            xg2 = (float)xp[2 * H_]; xg3 = (float)xp[3 * H_];
        }

        // prologue: stage K-tile 0 into As0
        *reinterpret_cast<f16x8*>(pool + AS0_OFF + sdst) =
            *reinterpret_cast<const f16x8*>(&hprev[(size_t)sr * hstr + soct * 8]);
        f32x4 acc0 = {0.f, 0.f, 0.f, 0.f}, acc1 = {0.f, 0.f, 0.f, 0.f};
        __syncthreads();

        KSTEP(0,  AS0_OFF, AS1_OFF)
        KSTEP(1,  AS1_OFF, AS0_OFF)
        KSTEP(2,  AS0_OFF, AS1_OFF)
        KSTEP(3,  AS1_OFF, AS0_OFF)
        KSTEP(4,  AS0_OFF, AS1_OFF)
        KSTEP(5,  AS1_OFF, AS0_OFF)
        KSTEP(6,  AS0_OFF, AS1_OFF)
        KSTEP(7,  AS1_OFF, AS0_OFF)
        KSTEP(8,  AS0_OFF, AS1_OFF)
        KSTEP(9,  AS1_OFF, AS0_OFF)
        KSTEP(10, AS0_OFF, AS1_OFF)
        KSTEP(11, AS1_OFF, AS0_OFF)
        KSTEP(12, AS0_OFF, AS1_OFF)
        KSTEP(13, AS1_OFF, AS0_OFF)
        KSTEP(14, AS0_OFF, AS1_OFF)
        KSTEP(15, AS1_OFF, AS0_OFF)   // no prefetch/write (guarded); trailing sync
                                       // -> all A-buffer reads done, gl overlay safe

        // park per-expert partials into gl (overlays As0/As1)
#pragma unroll
        for (int j = 0; j < 4; ++j) {
            int r0 = mh * 32 + (lane >> 4) * 4 + j;
            gl[(ex * 64 + r0) * 17 + l15]      = acc0[j];
            gl[(ex * 64 + r0 + 16) * 17 + l15] = acc1[j];
        }
        __syncthreads();

        // mix experts + cell update (threads 0..255)
        if (tid < 256) {
            float gate[4];
#pragma unroll
            for (int g = 0; g < 4; ++g) {
                int nn = g * 4 + cl;
                gate[g] = cf4.x * gl[(0 * 64 + bb) * 17 + nn] +
                          cf4.y * gl[(1 * 64 + bb) * 17 + nn] +
                          cf4.z * gl[(2 * 64 + bb) * 17 + nn] +
                          cf4.w * gl[(3 * 64 + bb) * 17 + nn];
            }
            gate[0] += xg0; gate[1] += xg1; gate[2] += xg2; gate[3] += xg3;
            float cn = sigmoidf_(gate[1]) * c_reg + sigmoidf_(gate[0]) * tanhf(gate[2]);
            float hn = sigmoidf_(gate[3]) * tanhf(cn);
            c_reg = cn;
            xi[((size_t)t * B_ + bb) * G4 + col] = (f16)hn;   // h[t] overlay
            if (t == T_ - 1) {
                out[(size_t)T_ * B_ * C_ + bb * H_ + col] = hn;
                out[(size_t)T_ * B_ * C_ + B_ * H_ + bb * H_ + col] = cn;
            }
        }
        if (t != T_ - 1) grid_barrier(bar, t, jb);
    }
}

// ---------------- output projection ------------------------------------------
__global__ __launch_bounds__(256, 1) void k_out_gemm(
        const f16* __restrict__ hs, const f16* __restrict__ Woh,
        const float* __restrict__ coef, const float* __restrict__ bom,
        float* __restrict__ out) {
    __shared__ f16 As[64 * 72];
    __shared__ f16 Bs[256 * 72];
    __shared__ float cfs[64][4];
    const int nt = blockIdx.x;   // 0..1
    const int t  = blockIdx.y;   // 0..255
    const int tid = threadIdx.x, lane = tid & 63, w = tid >> 6;
    cfs[tid >> 2][tid & 3] = coef[tid];

    f32x4 acc[4][4];
#pragma unroll
    for (int e = 0; e < 4; ++e)
#pragma unroll
        for (int mi = 0; mi < 4; ++mi) acc[e][mi] = 0.f;

    for (int kk = 0; kk < H_; kk += 64) {
        __syncthreads();
#pragma unroll
        for (int it = 0; it < 2; ++it) {   // A: hs[t] 64x64 (stride G4 overlay)
            int chunk = it * 256 + tid;
            int row = chunk >> 3, c8 = chunk & 7;
            *reinterpret_cast<f16x8*>(&As[row * 72 + c8 * 8]) =
                *reinterpret_cast<const f16x8*>(&hs[((size_t)t * B_ + row) * G4 + kk + c8 * 8]);
        }
#pragma unroll
        for (int it = 0; it < 8; ++it) {   // B: Wo rows e*C + nt*64 + n
            int chunk = it * 256 + tid;
            int r = chunk >> 3, c8 = chunk & 7;
            int e = r >> 6, nn = r & 63;
            size_t grow = (size_t)e * C_ + nt * 64 + nn;
            *reinterpret_cast<f16x8*>(&Bs[r * 72 + c8 * 8]) =
                *reinterpret_cast<const f16x8*>(&Woh[grow * H_ + kk + c8 * 8]);
        }
        __syncthreads();
#pragma unroll
        for (int ks = 0; ks < 2; ++ks) {
            int ko = ks * 32 + (lane >> 4) * 8;
            f16x8 a[4];
#pragma unroll
            for (int mi = 0; mi < 4; ++mi)
                a[mi] = *reinterpret_cast<const f16x8*>(&As[(mi * 16 + (lane & 15)) * 72 + ko]);
#pragma unroll
            for (int e = 0; e < 4; ++e) {
                f16x8 bf = *reinterpret_cast<const f16x8*>(&Bs[(e * 64 + w * 16 + (lane & 15)) * 72 + ko]);
#pragma unroll
                for (int mi = 0; mi < 4; ++mi)
                    acc[e][mi] = __builtin_amdgcn_mfma_f32_16x16x32_f16(a[mi], bf, acc[e][mi], 0, 0, 0);
            }
        }
    }
#pragma unroll
    for (int mi = 0; mi < 4; ++mi)
#pragma unroll
        for (int j = 0; j < 4; ++j) {
            int bb = mi * 16 + (lane >> 4) * 4 + j;
            int cc = nt * 64 + w * 16 + (lane & 15);
            float v = cfs[bb][0] * acc[0][mi][j] + cfs[bb][1] * acc[1][mi][j] +
                      cfs[bb][2] * acc[2][mi][j] + cfs[bb][3] * acc[3][mi][j];
            v += bom[bb * C_ + cc];
            out[((size_t)t * B_ + bb) * C_ + cc] = v;
        }
}

extern "C" void kernel_launch(void* const* d_in, const int* in_sizes, int n_in,
                              void* d_out, int out_size, void* d_ws, size_t ws_size,
                              hipStream_t stream) {
    const float* x    = (const float*)d_in[0];
    const float* h0   = (const float*)d_in[1];
    const float* c0   = (const float*)d_in[2];
    const float* coef = (const float*)d_in[3];
    const float* Wi   = (const float*)d_in[4];
    const float* bi   = (const float*)d_in[5];
    const float* Wh   = (const float*)d_in[6];
    const float* bh   = (const float*)d_in[7];
    const float* Wo   = (const float*)d_in[8];
    const float* bo   = (const float*)d_in[9];
    float* out = (float*)d_out;

    char* base = (char*)d_ws;
    size_t off = 0;
    auto carve = [&](size_t bytes) -> char* {
        char* r = base + off;
        off = (off + bytes + 255) & ~(size_t)255;
        return r;
    };
    const size_t SZ_XI  = (size_t)T_ * B_ * G4 * 2;   // 134.2 MB (gate-0 doubles as hs)
    const size_t SZ_WOH = (size_t)E_ * C_ * H_ * 2;   // 1 MB
    const size_t SZ_BAR = (size_t)T_ * 9 * 4;         // barrier counters
    const size_t SZ_WIH = (size_t)E_ * G4 * I_ * 2;   // 33.5 MB (optional)
    const size_t SZ_XH  = (size_t)T_ * B_ * I_ * 2;   // 33.5 MB (optional)

    f16*   xi     = (f16*)carve(SZ_XI);
    f16*   Woh    = (f16*)carve(SZ_WOH);
    f16*   h0h    = (f16*)carve((size_t)B_ * H_ * 2);
    float* gbias  = (float*)carve((size_t)B_ * G4 * 4);
    float* bom    = (float*)carve((size_t)B_ * C_ * 4);
    int*   bar    = (int*)carve(SZ_BAR);

    f16* Wih = nullptr;
    f16* xh  = nullptr;
    if (off + SZ_WIH + 256 <= ws_size) Wih = (f16*)carve(SZ_WIH);
    if (Wih && off + SZ_XH + 256 <= ws_size) xh = (f16*)carve(SZ_XH);
    (void)in_sizes; (void)n_in; (void)out_size;

    hipMemsetAsync(bar, 0, SZ_BAR, stream);

    if (xh)  k_f32_to_f16<<<2048, 256, 0, stream>>>(x,  xh,  (T_ * B_ * I_) / 8);
    if (Wih) k_f32_to_f16<<<2048, 256, 0, stream>>>(Wi, Wih, (E_ * G4 * I_) / 8);
    k_f32_to_f16<<<512,  256, 0, stream>>>(Wo, Woh, (E_ * C_ * H_) / 8);
    k_mix_biases<<<512, 256, 0, stream>>>(coef, bi, bh, bo, gbias, bom);
    k_init_h0h<<<(B_ * H_ + 255) / 256, 256, 0, stream>>>(h0, h0h);

    dim3 gx(32, 64);
    if (xh)
        k_xi_gemm<true,  true ><<<gx, 256, 0, stream>>>(xh, nullptr, Wih, nullptr, coef, gbias, xi);
    else if (Wih)
        k_xi_gemm<false, true ><<<gx, 256, 0, stream>>>(nullptr, x, Wih, nullptr, coef, gbias, xi);
    else
        k_xi_gemm<false, false><<<gx, 256, 0, stream>>>(nullptr, x, nullptr, Wi, coef, gbias, xi);

    // persistent recurrence: one cooperative launch, 256 blocks x 512 threads
    {
        void* args[] = { (void*)&Wh, (void*)&h0h, (void*)&c0, (void*)&xi,
                         (void*)&coef, (void*)&out, (void*)&bar };
        hipLaunchCooperativeKernel((const void*)k_rec_persist, dim3(256), dim3(512),
                                   args, 0, stream);
    }

    dim3 go(2, 256);
    k_out_gemm<<<go, 256, 0, stream>>>(xi, Woh, coef, bom, out);
}

// Round 9
// 3543.874 us; speedup vs baseline: 4.2703x; 4.2048x over previous
//
#include <hip/hip_runtime.h>
#include <hip/hip_fp16.h>
#include <cstdint>

// Problem constants
#define T_  256
#define B_  64
#define I_  1024
#define H_  1024
#define E_  4
#define C_  128
#define G4  4096   // 4*H

typedef _Float16 f16;
typedef _Float16 f16x8 __attribute__((ext_vector_type(8)));
typedef float    f32x4 __attribute__((ext_vector_type(4)));

__device__ __forceinline__ float sigmoidf_(float x) { return 1.f / (1.f + __expf(-x)); }

// ---------------- conversion f32 -> f16 (vectorized, grid-stride) -------------
__global__ void k_f32_to_f16(const float* __restrict__ src, f16* __restrict__ dst, int n8) {
    int i = blockIdx.x * blockDim.x + threadIdx.x;
    int stride = gridDim.x * blockDim.x;
    for (; i < n8; i += stride) {
        const float4* s = reinterpret_cast<const float4*>(src) + (size_t)i * 2;
        float4 a = s[0], b = s[1];
        f16x8 v = { (f16)a.x, (f16)a.y, (f16)a.z, (f16)a.w,
                    (f16)b.x, (f16)b.y, (f16)b.z, (f16)b.w };
        *reinterpret_cast<f16x8*>(dst + (size_t)i * 8) = v;
    }
}

// ---------------- Wh permute: f32 [e][4H][H] -> f16 Whp[jb][32][1024] ---------
// Block jb (0..511) owns h-cols jb*2, jb*2+1; its 32 rows (r = e*8+g*2+c) are
// CONTIGUOUS in Whp so per-step staging is a pure coalesced stream.
__global__ void k_permute_wh(const float* __restrict__ Wh, f16* __restrict__ Whp) {
    int idx = blockIdx.x * blockDim.x + threadIdx.x;
    int stride = gridDim.x * blockDim.x;
    const int total = 512 * 32 * 128;          // f16x8 chunks
    for (; idx < total; idx += stride) {
        int oct = idx & 127, rem = idx >> 7;
        int r = rem & 31, jb = rem >> 5;
        int e = r >> 3, g = (r >> 1) & 3, c = r & 1;
        const float* src = &Wh[((size_t)e * G4 + g * H_ + jb * 2 + c) * H_ + oct * 8];
        float4 f0 = *reinterpret_cast<const float4*>(src);
        float4 f1 = *reinterpret_cast<const float4*>(src + 4);
        f16x8 v = { (f16)f0.x, (f16)f0.y, (f16)f0.z, (f16)f0.w,
                    (f16)f1.x, (f16)f1.y, (f16)f1.z, (f16)f1.w };
        *reinterpret_cast<f16x8*>(&Whp[((size_t)jb * 32 + r) * 1024 + oct * 8]) = v;
    }
}

// ---------------- mixed biases: gbias = coef@(bi+bh), bom = coef@bo ----------
__global__ void k_mix_biases(const float* __restrict__ coef, const float* __restrict__ bi,
                             const float* __restrict__ bh, const float* __restrict__ bo,
                             float* __restrict__ gbias, float* __restrict__ bom) {
    int idx = blockIdx.x * blockDim.x + threadIdx.x;
    int stride = gridDim.x * blockDim.x;
    for (int i = idx; i < B_ * G4; i += stride) {
        int b = i >> 12, o = i & (G4 - 1);
        float s = 0.f;
#pragma unroll
        for (int e = 0; e < 4; ++e) s += coef[b * 4 + e] * (bi[e * G4 + o] + bh[e * G4 + o]);
        gbias[i] = s;
    }
    for (int i = idx; i < B_ * C_; i += stride) {
        int b = i >> 7, c = i & (C_ - 1);
        float s = 0.f;
#pragma unroll
        for (int e = 0; e < 4; ++e) s += coef[b * 4 + e] * bo[e * C_ + c];
        bom[i] = s;
    }
}

// ---------------- state init: h0 -> f16, c0 -> cstate ------------------------
__global__ void k_init_state(const float* __restrict__ h0, const float* __restrict__ c0,
                             f16* __restrict__ h0h, float* __restrict__ cstate) {
    int i = blockIdx.x * blockDim.x + threadIdx.x;
    if (i < B_ * H_) { h0h[i] = (f16)h0[i]; cstate[i] = c0[i]; }
}

// ---------------- xi GEMM: per-sample mixed input projection -----------------
template<bool XF16, bool WF16>
__global__ __launch_bounds__(256, 1) void k_xi_gemm(
        const f16* __restrict__ xh, const float* __restrict__ xf,
        const f16* __restrict__ Wih, const float* __restrict__ Wif,
        const float* __restrict__ coef, const float* __restrict__ gbias,
        f16* __restrict__ xi) {
    __shared__ f16 As[256 * 72];
    __shared__ f16 Bs[128 * 72];
    const int nt = blockIdx.x;      // 0..31  (128-col tile of 4096)
    const int b  = blockIdx.y;      // 0..63
    const int tid = threadIdx.x;
    const int lane = tid & 63, wave = tid >> 6;
    const int wr = wave >> 1, wc = wave & 1;

    float cf[4];
#pragma unroll
    for (int e = 0; e < 4; ++e) cf[e] = coef[b * 4 + e];

    f32x4 acc[8][4];
#pragma unroll
    for (int mi = 0; mi < 8; ++mi)
#pragma unroll
        for (int ni = 0; ni < 4; ++ni) acc[mi][ni] = 0.f;

    for (int kk = 0; kk < I_; kk += 64) {
        __syncthreads();
#pragma unroll
        for (int it = 0; it < 8; ++it) {
            int chunk = it * 256 + tid;
            int row = chunk >> 3, c8 = chunk & 7;
            if constexpr (XF16) {
                *reinterpret_cast<f16x8*>(&As[row * 72 + c8 * 8]) =
                    *reinterpret_cast<const f16x8*>(&xh[((size_t)row * B_ + b) * I_ + kk + c8 * 8]);
            } else {
                const float4* p = reinterpret_cast<const float4*>(&xf[((size_t)row * B_ + b) * I_ + kk + c8 * 8]);
                float4 a = p[0], bq = p[1];
                f16x8 v = { (f16)a.x, (f16)a.y, (f16)a.z, (f16)a.w,
                            (f16)bq.x, (f16)bq.y, (f16)bq.z, (f16)bq.w };
                *reinterpret_cast<f16x8*>(&As[row * 72 + c8 * 8]) = v;
            }
        }
#pragma unroll
        for (int it = 0; it < 4; ++it) {
            int chunk = it * 256 + tid;
            int n = chunk >> 3, c8 = chunk & 7;
            if constexpr (WF16) {
                size_t base = ((size_t)(nt * 128 + n)) * I_ + kk + c8 * 8;
                f16 c0 = (f16)cf[0], c1 = (f16)cf[1], c2 = (f16)cf[2], c3 = (f16)cf[3];
                f16x8 w0 = *reinterpret_cast<const f16x8*>(&Wih[base]);
                f16x8 w1 = *reinterpret_cast<const f16x8*>(&Wih[base + (size_t)1 * G4 * I_]);
                f16x8 w2 = *reinterpret_cast<const f16x8*>(&Wih[base + (size_t)2 * G4 * I_]);
                f16x8 w3 = *reinterpret_cast<const f16x8*>(&Wih[base + (size_t)3 * G4 * I_]);
                f16x8 m = w0 * c0 + w1 * c1 + w2 * c2 + w3 * c3;
                *reinterpret_cast<f16x8*>(&Bs[n * 72 + c8 * 8]) = m;
            } else {
                size_t base = ((size_t)(nt * 128 + n)) * I_ + kk + c8 * 8;
                float m[8];
#pragma unroll
                for (int j = 0; j < 8; ++j) m[j] = 0.f;
#pragma unroll
                for (int e = 0; e < 4; ++e) {
                    const float4* p = reinterpret_cast<const float4*>(&Wif[base + (size_t)e * G4 * I_]);
                    float4 a = p[0], bq = p[1];
                    m[0] += cf[e] * a.x;  m[1] += cf[e] * a.y;
                    m[2] += cf[e] * a.z;  m[3] += cf[e] * a.w;
                    m[4] += cf[e] * bq.x; m[5] += cf[e] * bq.y;
                    m[6] += cf[e] * bq.z; m[7] += cf[e] * bq.w;
                }
                f16x8 v = { (f16)m[0], (f16)m[1], (f16)m[2], (f16)m[3],
                            (f16)m[4], (f16)m[5], (f16)m[6], (f16)m[7] };
                *reinterpret_cast<f16x8*>(&Bs[n * 72 + c8 * 8]) = v;
            }
        }
        __syncthreads();
#pragma unroll
        for (int ks = 0; ks < 2; ++ks) {
            int ko = ks * 32 + (lane >> 4) * 8;
            f16x8 a[8], bb[4];
#pragma unroll
            for (int mi = 0; mi < 8; ++mi)
                a[mi] = *reinterpret_cast<const f16x8*>(&As[(wr * 128 + mi * 16 + (lane & 15)) * 72 + ko]);
#pragma unroll
            for (int ni = 0; ni < 4; ++ni)
                bb[ni] = *reinterpret_cast<const f16x8*>(&Bs[(wc * 64 + ni * 16 + (lane & 15)) * 72 + ko]);
#pragma unroll
            for (int mi = 0; mi < 8; ++mi)
#pragma unroll
                for (int ni = 0; ni < 4; ++ni)
                    acc[mi][ni] = __builtin_amdgcn_mfma_f32_16x16x32_f16(a[mi], bb[ni], acc[mi][ni], 0, 0, 0);
        }
    }
#pragma unroll
    for (int mi = 0; mi < 8; ++mi)
#pragma unroll
        for (int ni = 0; ni < 4; ++ni)
#pragma unroll
            for (int j = 0; j < 4; ++j) {
                int t = wr * 128 + mi * 16 + (lane >> 4) * 4 + j;
                int o = nt * 128 + wc * 64 + ni * 16 + (lane & 15);
                float v = acc[mi][ni][j] + gbias[b * G4 + o];
                xi[((size_t)t * B_ + b) * G4 + o] = (f16)v;
            }
}

// ---------------- recurrence step (512 blocks = 2/CU, per-step launch) -------
// Block jb owns h-cols jb*2, jb*2+1: GEMM M=64(b) x N=32(e,g,c) x K=1024 vs
// h_prev, B-slice contiguous in Whp. 4 waves = M-quarters. Reg-prefetch
// double-buffered LDS tiles, one sync/K-tile. Epilogue operands loaded at
// kernel start (latency hidden). h[t] overlays xi[t] gate-0 cols jb*2..+1
// (disjoint across blocks; kernel boundary gives cross-step coherence).
__global__ __launch_bounds__(256, 2) void k_rec_step(
        int t, const f16* __restrict__ Whp, const f16* __restrict__ h0h,
        f16* xi, const float* __restrict__ coef,
        float* __restrict__ cstate, float* __restrict__ out) {
    __shared__ f16 As[2][64 * 72];
    __shared__ f16 Bs[2][32 * 72];
    __shared__ float gl[64][33];
    __shared__ float cfs[64][4];
    const int jb = blockIdx.x;                 // 0..511
    const int tid = threadIdx.x, lane = tid & 63, w = tid >> 6;   // w = M-quarter
    const int l15 = lane & 15, hi = lane >> 4;

    cfs[tid >> 2][tid & 3] = coef[tid];

    const f16* hprev = (t == 0) ? h0h : (xi + (size_t)(t - 1) * B_ * G4);
    const size_t hstr = (t == 0) ? (size_t)H_ : (size_t)G4;
    const f16* bsrc = Whp + (size_t)jb * 32 * 1024;

    // early epilogue operands (threads 0..127: p -> b = p>>1, c = p&1)
    const int bb = tid >> 1, cc = tid & 1;
    const int col = jb * 2 + cc;
    float c_old = 0.f, xg0 = 0.f, xg1 = 0.f, xg2 = 0.f, xg3 = 0.f;
    if (tid < 128) {
        c_old = cstate[bb * H_ + col];
        const f16* xp = &xi[((size_t)t * B_ + bb) * G4 + col];
        xg0 = (float)xp[0];      xg1 = (float)xp[H_];
        xg2 = (float)xp[2 * H_]; xg3 = (float)xp[3 * H_];
    }

    // prologue: stage K-tile 0
#pragma unroll
    for (int it = 0; it < 2; ++it) {
        int ch = it * 256 + tid, row = ch >> 3, oct = ch & 7;
        *reinterpret_cast<f16x8*>(&As[0][row * 72 + oct * 8]) =
            *reinterpret_cast<const f16x8*>(&hprev[(size_t)row * hstr + oct * 8]);
    }
    {
        int row = tid >> 3, oct = tid & 7;
        *reinterpret_cast<f16x8*>(&Bs[0][row * 72 + oct * 8]) =
            *reinterpret_cast<const f16x8*>(&bsrc[row * 1024 + oct * 8]);
    }
    f32x4 acc0 = {0.f, 0.f, 0.f, 0.f}, acc1 = {0.f, 0.f, 0.f, 0.f};
    __syncthreads();

#pragma unroll
    for (int kk = 0; kk < 16; ++kk) {
        const int p = kk & 1;
        f16x8 pa0, pa1, pb;
        if (kk < 15) {   // prefetch tile kk+1 into regs
            int kc = (kk + 1) * 64;
            { int ch = tid,       row = ch >> 3, oct = ch & 7;
              pa0 = *reinterpret_cast<const f16x8*>(&hprev[(size_t)row * hstr + kc + oct * 8]); }
            { int ch = 256 + tid, row = ch >> 3, oct = ch & 7;
              pa1 = *reinterpret_cast<const f16x8*>(&hprev[(size_t)row * hstr + kc + oct * 8]); }
            { int row = tid >> 3, oct = tid & 7;
              pb  = *reinterpret_cast<const f16x8*>(&bsrc[row * 1024 + kc + oct * 8]); }
        }
#pragma unroll
        for (int ks = 0; ks < 2; ++ks) {
            int ko = ks * 32 + hi * 8;
            f16x8 a  = *reinterpret_cast<const f16x8*>(&As[p][(w * 16 + l15) * 72 + ko]);
            f16x8 b0 = *reinterpret_cast<const f16x8*>(&Bs[p][l15 * 72 + ko]);
            f16x8 b1 = *reinterpret_cast<const f16x8*>(&Bs[p][(16 + l15) * 72 + ko]);
            acc0 = __builtin_amdgcn_mfma_f32_16x16x32_f16(a, b0, acc0, 0, 0, 0);
            acc1 = __builtin_amdgcn_mfma_f32_16x16x32_f16(a, b1, acc1, 0, 0, 0);
        }
        if (kk < 15) {
            { int ch = tid,       row = ch >> 3, oct = ch & 7;
              *reinterpret_cast<f16x8*>(&As[p ^ 1][row * 72 + oct * 8]) = pa0; }
            { int ch = 256 + tid, row = ch >> 3, oct = ch & 7;
              *reinterpret_cast<f16x8*>(&As[p ^ 1][row * 72 + oct * 8]) = pa1; }
            { int row = tid >> 3, oct = tid & 7;
              *reinterpret_cast<f16x8*>(&Bs[p ^ 1][row * 72 + oct * 8]) = pb; }
        }
        __syncthreads();
    }

    // park: C row = w*16 + hi*4 + j (b), col = l15 / 16+l15 (n = e*8+g*2+c)
#pragma unroll
    for (int j = 0; j < 4; ++j) {
        int row = w * 16 + hi * 4 + j;
        gl[row][l15]      = acc0[j];
        gl[row][16 + l15] = acc1[j];
    }
    __syncthreads();

    // mix experts + cell update (threads 0..127)
    if (tid < 128) {
        float gate[4];
#pragma unroll
        for (int g = 0; g < 4; ++g) {
            int n0 = g * 2 + cc;
            gate[g] = cfs[bb][0] * gl[bb][n0] + cfs[bb][1] * gl[bb][8 + n0] +
                      cfs[bb][2] * gl[bb][16 + n0] + cfs[bb][3] * gl[bb][24 + n0];
        }
        gate[0] += xg0; gate[1] += xg1; gate[2] += xg2; gate[3] += xg3;
        float cn = sigmoidf_(gate[1]) * c_old + sigmoidf_(gate[0]) * tanhf(gate[2]);
        float hn = sigmoidf_(gate[3]) * tanhf(cn);
        cstate[bb * H_ + col] = cn;
        xi[((size_t)t * B_ + bb) * G4 + col] = (f16)hn;   // h[t] overlay (gate-0)
        if (t == T_ - 1) {
            out[(size_t)T_ * B_ * C_ + bb * H_ + col] = hn;
            out[(size_t)T_ * B_ * C_ + B_ * H_ + bb * H_ + col] = cn;
        }
    }
}

// ---------------- output projection ------------------------------------------
__global__ __launch_bounds__(256, 1) void k_out_gemm(
        const f16* __restrict__ hs, const f16* __restrict__ Woh,
        const float* __restrict__ coef, const float* __restrict__ bom,
        float* __restrict__ out) {
    __shared__ f16 As[64 * 72];
    __shared__ f16 Bs[256 * 72];
    __shared__ float cfs[64][4];
    const int nt = blockIdx.x;   // 0..1
    const int t  = blockIdx.y;   // 0..255
    const int tid = threadIdx.x, lane = tid & 63, w = tid >> 6;
    cfs[tid >> 2][tid & 3] = coef[tid];

    f32x4 acc[4][4];
#pragma unroll
    for (int e = 0; e < 4; ++e)
#pragma unroll
        for (int mi = 0; mi < 4; ++mi) acc[e][mi] = 0.f;

    for (int kk = 0; kk < H_; kk += 64) {
        __syncthreads();
#pragma unroll
        for (int it = 0; it < 2; ++it) {   // A: hs[t] 64x64 (stride G4 overlay)
            int chunk = it * 256 + tid;
            int row = chunk >> 3, c8 = chunk & 7;
            *reinterpret_cast<f16x8*>(&As[row * 72 + c8 * 8]) =
                *reinterpret_cast<const f16x8*>(&hs[((size_t)t * B_ + row) * G4 + kk + c8 * 8]);
        }
#pragma unroll
        for (int it = 0; it < 8; ++it) {   // B: Wo rows e*C + nt*64 + n
            int chunk = it * 256 + tid;
            int r = chunk >> 3, c8 = chunk & 7;
            int e = r >> 6, nn = r & 63;
            size_t grow = (size_t)e * C_ + nt * 64 + nn;
            *reinterpret_cast<f16x8*>(&Bs[r * 72 + c8 * 8]) =
                *reinterpret_cast<const f16x8*>(&Woh[grow * H_ + kk + c8 * 8]);
        }
        __syncthreads();
#pragma unroll
        for (int ks = 0; ks < 2; ++ks) {
            int ko = ks * 32 + (lane >> 4) * 8;
            f16x8 a[4];
#pragma unroll
            for (int mi = 0; mi < 4; ++mi)
                a[mi] = *reinterpret_cast<const f16x8*>(&As[(mi * 16 + (lane & 15)) * 72 + ko]);
#pragma unroll
            for (int e = 0; e < 4; ++e) {
                f16x8 bf = *reinterpret_cast<const f16x8*>(&Bs[(e * 64 + w * 16 + (lane & 15)) * 72 + ko]);
#pragma unroll
                for (int mi = 0; mi < 4; ++mi)
                    acc[e][mi] = __builtin_amdgcn_mfma_f32_16x16x32_f16(a[mi], bf, acc[e][mi], 0, 0, 0);
            }
        }
    }
#pragma unroll
    for (int mi = 0; mi < 4; ++mi)
#pragma unroll
        for (int j = 0; j < 4; ++j) {
            int bb = mi * 16 + (lane >> 4) * 4 + j;
            int cc = nt * 64 + w * 16 + (lane & 15);
            float v = cfs[bb][0] * acc[0][mi][j] + cfs[bb][1] * acc[1][mi][j] +
                      cfs[bb][2] * acc[2][mi][j] + cfs[bb][3] * acc[3][mi][j];
            v += bom[bb * C_ + cc];
            out[((size_t)t * B_ + bb) * C_ + cc] = v;
        }
}

extern "C" void kernel_launch(void* const* d_in, const int* in_sizes, int n_in,
                              void* d_out, int out_size, void* d_ws, size_t ws_size,
                              hipStream_t stream) {
    const float* x    = (const float*)d_in[0];
    const float* h0   = (const float*)d_in[1];
    const float* c0   = (const float*)d_in[2];
    const float* coef = (const float*)d_in[3];
    const float* Wi   = (const float*)d_in[4];
    const float* bi   = (const float*)d_in[5];
    const float* Wh   = (const float*)d_in[6];
    const float* bh   = (const float*)d_in[7];
    const float* Wo   = (const float*)d_in[8];
    const float* bo   = (const float*)d_in[9];
    float* out = (float*)d_out;

    char* base = (char*)d_ws;
    size_t off = 0;
    auto carve = [&](size_t bytes) -> char* {
        char* r = base + off;
        off = (off + bytes + 255) & ~(size_t)255;
        return r;
    };
    const size_t SZ_XI  = (size_t)T_ * B_ * G4 * 2;   // 134.2 MB (gate-0 doubles as hs)
    const size_t SZ_WHP = (size_t)512 * 32 * 1024 * 2; // 33.5 MB permuted Wh
    const size_t SZ_WOH = (size_t)E_ * C_ * H_ * 2;   // 1 MB
    const size_t SZ_WIH = (size_t)E_ * G4 * I_ * 2;   // 33.5 MB (optional)
    const size_t SZ_XH  = (size_t)T_ * B_ * I_ * 2;   // 33.5 MB (optional)

    f16*   xi     = (f16*)carve(SZ_XI);
    f16*   Whp    = (f16*)carve(SZ_WHP);
    f16*   Woh    = (f16*)carve(SZ_WOH);
    f16*   h0h    = (f16*)carve((size_t)B_ * H_ * 2);
    float* gbias  = (float*)carve((size_t)B_ * G4 * 4);
    float* bom    = (float*)carve((size_t)B_ * C_ * 4);
    float* cstate = (float*)carve((size_t)B_ * H_ * 4);

    f16* Wih = nullptr;
    f16* xh  = nullptr;
    if (off + SZ_WIH + 256 <= ws_size) Wih = (f16*)carve(SZ_WIH);
    if (Wih && off + SZ_XH + 256 <= ws_size) xh = (f16*)carve(SZ_XH);
    (void)in_sizes; (void)n_in; (void)out_size;

    if (xh)  k_f32_to_f16<<<2048, 256, 0, stream>>>(x,  xh,  (T_ * B_ * I_) / 8);
    if (Wih) k_f32_to_f16<<<2048, 256, 0, stream>>>(Wi, Wih, (E_ * G4 * I_) / 8);
    k_permute_wh<<<2048, 256, 0, stream>>>(Wh, Whp);
    k_f32_to_f16<<<512,  256, 0, stream>>>(Wo, Woh, (E_ * C_ * H_) / 8);
    k_mix_biases<<<512, 256, 0, stream>>>(coef, bi, bh, bo, gbias, bom);
    k_init_state<<<(B_ * H_ + 255) / 256, 256, 0, stream>>>(h0, c0, h0h, cstate);

    dim3 gx(32, 64);
    if (xh)
        k_xi_gemm<true,  true ><<<gx, 256, 0, stream>>>(xh, nullptr, Wih, nullptr, coef, gbias, xi);
    else if (Wih)
        k_xi_gemm<false, true ><<<gx, 256, 0, stream>>>(nullptr, x, Wih, nullptr, coef, gbias, xi);
    else
        k_xi_gemm<false, false><<<gx, 256, 0, stream>>>(nullptr, x, nullptr, Wi, coef, gbias, xi);

    // serial recurrence: per-step launches, 512 blocks (2/CU)
    for (int t = 0; t < T_; ++t)
        k_rec_step<<<512, 256, 0, stream>>>(t, Whp, h0h, xi, coef, cstate, out);

    dim3 go(2, 256);
    k_out_gemm<<<go, 256, 0, stream>>>(xi, Woh, coef, bom, out);
}